// Round 5
// baseline (154.589 us; speedup 1.0000x reference)
//
#include <hip/hip_runtime.h>

#define Bn 2
#define Hn 16
#define Tn 2048
#define Sn 2048
#define Wd 1024
#define Dh 64

typedef __attribute__((ext_vector_type(8))) short s16x8;
typedef __attribute__((ext_vector_type(4))) short s16x4;
typedef __attribute__((ext_vector_type(4))) float f32x4;
typedef __attribute__((ext_vector_type(4))) unsigned u32x4;

#define MFMA(a, b, c) __builtin_amdgcn_mfma_f32_16x16x32_bf16((a), (b), (c), 0, 0, 0)

__device__ __forceinline__ s16x8 ld8(const short* p) { return *(const s16x8*)p; }

// fp32 -> bf16 round-to-nearest-even
__device__ __forceinline__ short f2bf(float f) {
    unsigned u = __builtin_bit_cast(unsigned, f);
    u += 0x7FFFu + ((u >> 16) & 1u);
    return (short)(u >> 16);
}

// pack 2 f32 -> 2 bf16 (RNE) in one instruction
__device__ __forceinline__ unsigned cvtpk(float lo, float hi) {
    unsigned r;
    asm("v_cvt_pk_bf16_f32 %0, %1, %2" : "=v"(r) : "v"(lo), "v"(hi));
    return r;
}

// async global->LDS, 16B/lane: LDS dest = wave-uniform base + lane*16
__device__ __forceinline__ void gl_lds(const short* g, short* lds) {
    __builtin_amdgcn_global_load_lds(
        (const __attribute__((address_space(1))) void*)g,
        (__attribute__((address_space(3))) void*)lds, 16, 0, 0);
}

// ---------------------------------------------------------------------------
// prep: single launch doing all preprocessing.
//   blk <  1024 : K-pack  -> kp, MFMA A-frag order:
//                 group (bh, t16 = s/16, g): 64 lanes x 16B; lane l=(quad,l16),
//                 elem j = K[b][t16*16+l16][h*64 + g*32 + quad*8 + j]  (bf16)
//   blk <  2048 : V-pack  -> vp, MFMA B-frag order with s-permutation matched
//                 to attn's in-register P frags:
//                 group (bh, sc = s/64, nt, g): lane l, elem j =
//                 V[b][sc*64 + 16*(2g+(j>>2)) + quad*4 + (j&3)][h*64+nt*16+l16]
//   blk >= 2048 : w_proj fp32 -> bf16 bulk convert
// Fragment groups are contiguous 1KB: attn stages them with global_load_lds
// (linear lane*16 scatter) and reads them as conflict-free ds_read_b128.
// ---------------------------------------------------------------------------
__global__ __launch_bounds__(256) void prep(const float* __restrict__ ck,
                                            const float* __restrict__ cv,
                                            const float* __restrict__ wp,
                                            short* __restrict__ kp,
                                            short* __restrict__ vp,
                                            short* __restrict__ wb)
{
    __shared__ short T[64][72];   // 64x64 bf16 tile, stride 144B (9*16: b128-aligned)
    const int blk = blockIdx.x;
    const int tid = threadIdx.x;
    if (blk < 2048) {
        const int isV = blk >> 10;           // 0 = kpack, 1 = vpack
        const int c   = blk & 1023;
        const int bh = c >> 5, sc = c & 31;
        const int b = bh >> 4, h = bh & 15;
        const float* src = (isV ? cv : ck) + (size_t)(b * Sn + sc * 64) * Wd + h * Dh;
#pragma unroll
        for (int i = 0; i < 4; ++i) {
            int f = i * 256 + tid, sr = f >> 4, c4 = f & 15;
            float4 v = *(const float4*)(src + (size_t)sr * Wd + c4 * 4);
            s16x4 o;
            o[0] = f2bf(v.x); o[1] = f2bf(v.y); o[2] = f2bf(v.z); o[3] = f2bf(v.w);
            *(s16x4*)&T[sr][c4 * 4] = o;
        }
        __syncthreads();
        const int rt = tid >> 6;             // t16-local (K) or nt (V), 0..3
        const int l = tid & 63, quad = l >> 4, l16 = l & 15;
        if (!isV) {
            size_t base = ((size_t)((bh * 128 + sc * 4 + rt) * 2)) * 512 + l * 8;
            *(s16x8*)(kp + base)       = *(const s16x8*)&T[rt * 16 + l16][quad * 8];
            *(s16x8*)(kp + base + 512) = *(const s16x8*)&T[rt * 16 + l16][32 + quad * 8];
        } else {
#pragma unroll
            for (int g = 0; g < 2; ++g) {
                s16x8 o;
#pragma unroll
                for (int j = 0; j < 8; ++j) {
                    int s = 32 * g + 16 * (j >> 2) + quad * 4 + (j & 3);
                    o[j] = T[s][rt * 16 + l16];
                }
                *(s16x8*)(vp + ((size_t)((bh * 32 + sc) * 8 + rt * 2 + g)) * 512 + l * 8) = o;
            }
        }
    } else {
        int i = ((blk - 2048) * 256 + tid) * 8;
        float4 a = *(const float4*)(wp + i);
        float4 b = *(const float4*)(wp + i + 4);
        s16x8 o;
        o[0] = f2bf(a.x); o[1] = f2bf(a.y); o[2] = f2bf(a.z); o[3] = f2bf(a.w);
        o[4] = f2bf(b.x); o[5] = f2bf(b.y); o[6] = f2bf(b.z); o[7] = f2bf(b.w);
        *(s16x8*)(wb + i) = o;
    }
}

// ---------------------------------------------------------------------------
// Attention, 8-wave blocks (512 thr): wave w owns 16 q-rows; 2 blocks/CU x
// 8 waves = 16 waves/CU (was 8 -- grid is capped at 512 blocks by (b,h,qt),
// so occupancy comes from block size).  K/V staged as packed 1KB fragment
// groups via global_load_lds (wave w stages group w of K and V: 1+1 loads),
// double-buffered, one vmcnt(0)+barrier per 64-S chunk.  Fragments read as
// contiguous conflict-free ds_read_b128.  Per chunk per wave: stage(t+1) ->
// QK (8 MFMA, swapped: P in regs) -> exp2 + cvt_pk -> dn ones-MFMA (2) ->
// PV (8 MFMA).  Grid 512, blk%8 = bh%8 -> XCD L2 locality.
// ---------------------------------------------------------------------------
__global__ __launch_bounds__(512, 4) void attn_fused(
    const float* __restrict__ x, const short* __restrict__ kp,
    const short* __restrict__ vt, short* __restrict__ ao)
{
    __shared__ alignas(16) short Ks[2][8 * 512];   // 8KB per buffer
    __shared__ alignas(16) short Vs[2][8 * 512];   // 8KB per buffer

    const int tid  = threadIdx.x;
    const int w    = tid >> 6;               // 0..7
    const int l    = tid & 63;
    const int quad = l >> 4;
    const int l16  = l & 15;

    const int bh = blockIdx.x & 31;          // blk%8 = bh%8 -> XCD locality
    const int qt = blockIdx.x >> 5;
    const int b  = bh >> 4, h = bh & 15;

    const int qrow0 = qt * 128 + w * 16;

    const short* kp_h = kp + (size_t)bh * 131072;   // 128 t16 x 2 g x 512 shorts
    const short* vp_h = vt + (size_t)bh * 131072;   // 32 sc x 8 (nt,g) x 512 shorts

    // prologue: stage chunk 0 into buffer 0 (wave w stages group w of each)
    gl_lds(kp_h + (size_t)w * 512 + l * 8, &Ks[0][w * 512]);
    gl_lds(vp_h + (size_t)w * 512 + l * 8, &Vs[0][w * 512]);

    // Q B-frags from fp32, scaled by 0.125*log2e (folds 1/sqrt(d) and exp2 base)
    const float SQ = 0.125f * 1.4426950408889634f;
    s16x8 aq[2];
#pragma unroll
    for (int c = 0; c < 2; ++c) {
        const float* p = x + (size_t)(b * Tn + qrow0 + l16) * Wd
                           + h * Dh + c * 32 + quad * 8;
        float4 a = ((const float4*)p)[0], bb = ((const float4*)p)[1];
        s16x8 o;
        o[0] = f2bf(a.x * SQ); o[1] = f2bf(a.y * SQ); o[2] = f2bf(a.z * SQ); o[3] = f2bf(a.w * SQ);
        o[4] = f2bf(bb.x * SQ); o[5] = f2bf(bb.y * SQ); o[6] = f2bf(bb.z * SQ); o[7] = f2bf(bb.w * SQ);
        aq[c] = o;
    }

    f32x4 oacc[4], dnacc;
#pragma unroll
    for (int nt = 0; nt < 4; ++nt) {
        oacc[nt][0] = 0.f; oacc[nt][1] = 0.f;
        oacc[nt][2] = 0.f; oacc[nt][3] = 0.f;
    }
    dnacc[0] = 0.f; dnacc[1] = 0.f; dnacc[2] = 0.f; dnacc[3] = 0.f;

    s16x8 ones;
#pragma unroll
    for (int j = 0; j < 8; ++j) ones[j] = (short)0x3F80;   // bf16 1.0

    const f32x4 z = {0.f, 0.f, 0.f, 0.f};
    const int NIT = Sn / 64;

    // chunk-0 staging (and Q loads) must be complete before first reads
    asm volatile("s_waitcnt vmcnt(0)" ::: "memory");
    __syncthreads();

    for (int it = 0; it < NIT; ++it) {
        const int p = it & 1;

        // issue next chunk's staging into the alternate buffer
        if (it + 1 < NIT) {
            const size_t cbase = (size_t)(it + 1) * 8;
            gl_lds(kp_h + (cbase + w) * 512 + l * 8, &Ks[p ^ 1][w * 512]);
            gl_lds(vp_h + (cbase + w) * 512 + l * 8, &Vs[p ^ 1][w * 512]);
        }

        // ---- fragment reads: contiguous 1KB ds_read_b128, conflict-free ----
        s16x8 kf[4][2];
#pragma unroll
        for (int sj = 0; sj < 4; ++sj)
#pragma unroll
            for (int g = 0; g < 2; ++g)
                kf[sj][g] = *(const s16x8*)&Ks[p][(sj * 2 + g) * 512 + l * 8];

        // ---- QK (swapped): sc[sj] = K-tile(sj) . Q^T ----
        // lane (quad,l16): sc[sj][r] = scores[q=l16][s=sj*16+quad*4+r]
        f32x4 sc[4];
        __builtin_amdgcn_s_setprio(1);
#pragma unroll
        for (int sj = 0; sj < 4; ++sj) {
            sc[sj] = MFMA(kf[sj][0], aq[0], z);
            sc[sj] = MFMA(kf[sj][1], aq[1], sc[sj]);
        }
        __builtin_amdgcn_s_setprio(0);

        // ---- exp2 + pack to PV A-frags fully in-register ----
        s16x8 ap[2];
        {
            float ex[4][4];
#pragma unroll
            for (int sj = 0; sj < 4; ++sj)
#pragma unroll
                for (int r = 0; r < 4; ++r)
                    ex[sj][r] = __builtin_amdgcn_exp2f(sc[sj][r]);
#pragma unroll
            for (int g = 0; g < 2; ++g) {
                u32x4 pk;
                pk[0] = cvtpk(ex[2 * g][0],     ex[2 * g][1]);
                pk[1] = cvtpk(ex[2 * g][2],     ex[2 * g][3]);
                pk[2] = cvtpk(ex[2 * g + 1][0], ex[2 * g + 1][1]);
                pk[3] = cvtpk(ex[2 * g + 1][2], ex[2 * g + 1][3]);
                ap[g] = __builtin_bit_cast(s16x8, pk);
            }
        }

        // ---- V fragment reads ----
        s16x8 vf[4][2];
#pragma unroll
        for (int nt = 0; nt < 4; ++nt)
#pragma unroll
            for (int g = 0; g < 2; ++g)
                vf[nt][g] = *(const s16x8*)&Vs[p][(nt * 2 + g) * 512 + l * 8];

        // ---- denominator (ones-column MFMA) + PV ----
        __builtin_amdgcn_s_setprio(1);
        dnacc = MFMA(ap[0], ones, dnacc);
        dnacc = MFMA(ap[1], ones, dnacc);
#pragma unroll
        for (int nt = 0; nt < 4; ++nt) {
            oacc[nt] = MFMA(ap[0], vf[nt][0], oacc[nt]);
            oacc[nt] = MFMA(ap[1], vf[nt][1], oacc[nt]);
        }
        __builtin_amdgcn_s_setprio(0);

        // next buffer must be fully landed before any wave reads it
        asm volatile("s_waitcnt vmcnt(0)" ::: "memory");
        __syncthreads();
    }

    // epilogue: dnacc row q=quad*4+r already holds the denominator for that q
#pragma unroll
    for (int r = 0; r < 4; ++r) {
        float inv = 1.0f / dnacc[r];
        int t = qrow0 + quad * 4 + r;
#pragma unroll
        for (int nt = 0; nt < 4; ++nt)
            ao[(size_t)(b * Tn + t) * Wd + h * Dh + nt * 16 + l16] =
                f2bf(oacc[nt][r] * inv);
    }
}

#define LSTR 40   // proj LDS row stride (80 B = 5*16: b128-aligned, 2-way banks)

// ---------------------------------------------------------------------------
// Projection GEMM, double-buffered + async reg-staged prefetch, 1 barrier/iter:
// out[4096][1024] = A(bf16)[M][K] @ Wb(bf16)[N][K]^T + bias, fp32 out.
// Block 256 = 4 waves; tile 128m x 64n x 32k; wave = 64m x 32n (8 MFMA/chunk).
// ---------------------------------------------------------------------------
__global__ __launch_bounds__(256, 2) void proj_gemm(
    const short* __restrict__ A, const short* __restrict__ Wb,
    const float* __restrict__ bias, float* __restrict__ out)
{
    __shared__ alignas(16) short As[2][128 * LSTR];
    __shared__ alignas(16) short Bs[2][64 * LSTR];

    const int tid  = threadIdx.x;
    const int w    = tid >> 6;
    const int l    = tid & 63;
    const int quad = l >> 4;
    const int l16  = l & 15;

    const int bn = blockIdx.x & 15;    // 16 n-tiles
    const int bm = blockIdx.x >> 4;    // 32 m-tiles
    const int m0 = bm * 128;
    const int n0 = bn * 64;
    const int wm = (w & 1) * 64;       // wave m-offset
    const int wn = (w >> 1) * 32;      // wave n-offset

    const int rr = tid >> 2;   // staging row 0..63
    const int sg = tid & 3;    // 16B segment 0..3 (BK=32 shorts = 64B row)

    f32x4 acc[4][2];
#pragma unroll
    for (int mi = 0; mi < 4; ++mi)
#pragma unroll
        for (int nt = 0; nt < 2; ++nt) {
            acc[mi][nt][0] = 0.f; acc[mi][nt][1] = 0.f;
            acc[mi][nt][2] = 0.f; acc[mi][nt][3] = 0.f;
        }

    // prologue: stage k-chunk 0 into buffer 0
    s16x8 ra0 = ld8(A  + (size_t)(m0 + rr) * Wd + sg * 8);
    s16x8 ra1 = ld8(A  + (size_t)(m0 + 64 + rr) * Wd + sg * 8);
    s16x8 rb  = ld8(Wb + (size_t)(n0 + rr) * Wd + sg * 8);
    *(s16x8*)&As[0][rr * LSTR + sg * 8]        = ra0;
    *(s16x8*)&As[0][(rr + 64) * LSTR + sg * 8] = ra1;
    *(s16x8*)&Bs[0][rr * LSTR + sg * 8]        = rb;
    __syncthreads();

    for (int k0 = 0; k0 < Wd; k0 += 32) {
        const int p = (k0 >> 5) & 1;

        if (k0 + 32 < Wd) {
            ra0 = ld8(A  + (size_t)(m0 + rr) * Wd + k0 + 32 + sg * 8);
            ra1 = ld8(A  + (size_t)(m0 + 64 + rr) * Wd + k0 + 32 + sg * 8);
            rb  = ld8(Wb + (size_t)(n0 + rr) * Wd + k0 + 32 + sg * 8);
        }

        s16x8 a[4], bw[2];
#pragma unroll
        for (int mi = 0; mi < 4; ++mi)
            a[mi] = *(const s16x8*)&As[p][(wm + mi * 16 + l16) * LSTR + quad * 8];
#pragma unroll
        for (int nt = 0; nt < 2; ++nt)
            bw[nt] = *(const s16x8*)&Bs[p][(wn + nt * 16 + l16) * LSTR + quad * 8];
        __builtin_amdgcn_s_setprio(1);
#pragma unroll
        for (int mi = 0; mi < 4; ++mi)
#pragma unroll
            for (int nt = 0; nt < 2; ++nt)
                acc[mi][nt] = MFMA(a[mi], bw[nt], acc[mi][nt]);
        __builtin_amdgcn_s_setprio(0);

        if (k0 + 32 < Wd) {
            *(s16x8*)&As[p ^ 1][rr * LSTR + sg * 8]        = ra0;
            *(s16x8*)&As[p ^ 1][(rr + 64) * LSTR + sg * 8] = ra1;
            *(s16x8*)&Bs[p ^ 1][rr * LSTR + sg * 8]        = rb;
        }
        __syncthreads();
    }

#pragma unroll
    for (int nt = 0; nt < 2; ++nt) {
        float bv = bias[n0 + wn + nt * 16 + l16];
#pragma unroll
        for (int mi = 0; mi < 4; ++mi)
#pragma unroll
            for (int r = 0; r < 4; ++r)
                out[(size_t)(m0 + wm + mi * 16 + quad * 4 + r) * Wd + n0 + wn + nt * 16 + l16] =
                    acc[mi][nt][r] + bv;
    }
}

extern "C" void kernel_launch(void* const* d_in, const int* in_sizes, int n_in,
                              void* d_out, int out_size, void* d_ws, size_t ws_size,
                              hipStream_t stream) {
    const float* x  = (const float*)d_in[0];   // [2,2048,1024] fp32
    const float* ck = (const float*)d_in[1];   // [2,2048,1024] fp32
    const float* cv = (const float*)d_in[2];   // [2,2048,1024] fp32
    const float* wp = (const float*)d_in[3];   // [1024,1024]   fp32
    const float* bp = (const float*)d_in[4];   // [1024]        fp32

    const int nX = Bn * Tn * Wd;   // 4,194,304
    const int nW = Wd * Wd;        // 1,048,576

    short* kpb = (short*)d_ws;     // 8 MB  (K, MFMA A-frag packed)
    short* vpb = kpb + nX;         // 8 MB  (V^T, MFMA B-frag packed + s-perm)
    short* wbb = vpb + nX;         // 2 MB  (Wp bf16)
    short* am  = wbb + nW;         // 8 MB  (attention output, bf16)

    prep<<<dim3(2048 + nW / 2048), dim3(256), 0, stream>>>(ck, cv, wp, kpb, vpb, wbb);

    attn_fused<<<dim3(Bn * Hn * (Tn / 128)), dim3(512), 0, stream>>>(x, kpb, vpb, am);
    proj_gemm<<<dim3((Bn * Tn / 128) * (Wd / 64)), dim3(256), 0, stream>>>(
        am, wbb, bp, (float*)d_out);
}

// Round 7
// 153.844 us; speedup vs baseline: 1.0048x; 1.0048x over previous
//
#include <hip/hip_runtime.h>

#define Bn 2
#define Hn 16
#define Tn 2048
#define Sn 2048
#define Wd 1024
#define Dh 64

typedef __attribute__((ext_vector_type(8))) short s16x8;
typedef __attribute__((ext_vector_type(4))) short s16x4;
typedef __attribute__((ext_vector_type(4))) float f32x4;
typedef __attribute__((ext_vector_type(4))) unsigned u32x4;

#define MFMA(a, b, c) __builtin_amdgcn_mfma_f32_16x16x32_bf16((a), (b), (c), 0, 0, 0)

__device__ __forceinline__ s16x8 ld8(const short* p) { return *(const s16x8*)p; }

// fp32 -> bf16 round-to-nearest-even
__device__ __forceinline__ short f2bf(float f) {
    unsigned u = __builtin_bit_cast(unsigned, f);
    u += 0x7FFFu + ((u >> 16) & 1u);
    return (short)(u >> 16);
}

// pack 2 f32 -> 2 bf16 (RNE) in one instruction
__device__ __forceinline__ unsigned cvtpk(float lo, float hi) {
    unsigned r;
    asm("v_cvt_pk_bf16_f32 %0, %1, %2" : "=v"(r) : "v"(lo), "v"(hi));
    return r;
}

// async global->LDS, 16B/lane: LDS dest = wave-uniform base + lane*16
__device__ __forceinline__ void gl_lds(const short* g, short* lds) {
    __builtin_amdgcn_global_load_lds(
        (const __attribute__((address_space(1))) void*)g,
        (__attribute__((address_space(3))) void*)lds, 16, 0, 0);
}

// ---------------------------------------------------------------------------
// prep: single launch doing all preprocessing.
//   blk <  1024 : K-pack  -> kp, MFMA A-frag order:
//                 group (bh, t16 = s/16, g): 64 lanes x 16B; lane l=(quad,l16),
//                 elem j = K[b][t16*16+l16][h*64 + g*32 + quad*8 + j]  (bf16)
//   blk <  2048 : V-pack  -> vp, MFMA B-frag order with s-permutation matched
//                 to attn's in-register P frags:
//                 group (bh, sc = s/64, nt, g): lane l, elem j =
//                 V[b][sc*64 + 16*(2g+(j>>2)) + quad*4 + (j&3)][h*64+nt*16+l16]
//   blk >= 2048 : w_proj fp32 -> bf16 bulk convert
// Fragment groups are contiguous 1KB: attn stages them with global_load_lds
// (linear lane*16 scatter) and reads them as conflict-free ds_read_b128.
// ---------------------------------------------------------------------------
__global__ __launch_bounds__(256) void prep(const float* __restrict__ ck,
                                            const float* __restrict__ cv,
                                            const float* __restrict__ wp,
                                            short* __restrict__ kp,
                                            short* __restrict__ vp,
                                            short* __restrict__ wb)
{
    __shared__ short T[64][72];   // 64x64 bf16 tile, stride 144B (9*16: b128-aligned)
    const int blk = blockIdx.x;
    const int tid = threadIdx.x;
    if (blk < 2048) {
        const int isV = blk >> 10;           // 0 = kpack, 1 = vpack
        const int c   = blk & 1023;
        const int bh = c >> 5, sc = c & 31;
        const int b = bh >> 4, h = bh & 15;
        const float* src = (isV ? cv : ck) + (size_t)(b * Sn + sc * 64) * Wd + h * Dh;
#pragma unroll
        for (int i = 0; i < 4; ++i) {
            int f = i * 256 + tid, sr = f >> 4, c4 = f & 15;
            float4 v = *(const float4*)(src + (size_t)sr * Wd + c4 * 4);
            s16x4 o;
            o[0] = f2bf(v.x); o[1] = f2bf(v.y); o[2] = f2bf(v.z); o[3] = f2bf(v.w);
            *(s16x4*)&T[sr][c4 * 4] = o;
        }
        __syncthreads();
        const int rt = tid >> 6;             // t16-local (K) or nt (V), 0..3
        const int l = tid & 63, quad = l >> 4, l16 = l & 15;
        if (!isV) {
            size_t base = ((size_t)((bh * 128 + sc * 4 + rt) * 2)) * 512 + l * 8;
            *(s16x8*)(kp + base)       = *(const s16x8*)&T[rt * 16 + l16][quad * 8];
            *(s16x8*)(kp + base + 512) = *(const s16x8*)&T[rt * 16 + l16][32 + quad * 8];
        } else {
#pragma unroll
            for (int g = 0; g < 2; ++g) {
                s16x8 o;
#pragma unroll
                for (int j = 0; j < 8; ++j) {
                    int s = 32 * g + 16 * (j >> 2) + quad * 4 + (j & 3);
                    o[j] = T[s][rt * 16 + l16];
                }
                *(s16x8*)(vp + ((size_t)((bh * 32 + sc) * 8 + rt * 2 + g)) * 512 + l * 8) = o;
            }
        }
    } else {
        int i = ((blk - 2048) * 256 + tid) * 8;
        float4 a = *(const float4*)(wp + i);
        float4 b = *(const float4*)(wp + i + 4);
        s16x8 o;
        o[0] = f2bf(a.x); o[1] = f2bf(a.y); o[2] = f2bf(a.z); o[3] = f2bf(a.w);
        o[4] = f2bf(b.x); o[5] = f2bf(b.y); o[6] = f2bf(b.z); o[7] = f2bf(b.w);
        *(s16x8*)(wb + i) = o;
    }
}

// ---------------------------------------------------------------------------
// Attention, S-parity split: 8 waves (512 thr); wave w = (q-subtile w&3 of
// 32 rows, s-parity w>>2).  Each wave processes HALF the 64-S chunks with
// 32 q-rows -> per-wave LDS read halves (256 KB vs R5's 512 KB) while
// keeping 16 waves/CU.  Per-CU LDS-read = 4 MB = ~49k cy ~ MFMA 45k cy
// (R5 was 8 MB = 98k cy = the measured wall).
// K/V staged as packed 1KB fragment groups via global_load_lds into
// [superbuf][parity] slots (4 gl_lds/wave per super-iter); one
// vmcnt(0)+barrier per super-iter (2 chunks).  Partial O/dn combined
// across parity partners through LDS at the end.
// Grid 512, blk%8 = bh%8 -> XCD L2 locality.
// ---------------------------------------------------------------------------
__global__ __launch_bounds__(512, 4) void attn_fused(
    const float* __restrict__ x, const short* __restrict__ kp,
    const short* __restrict__ vt, short* __restrict__ ao)
{
    __shared__ alignas(16) short Ks[2][2][8 * 512];   // [superbuf][parity] 32KB
    __shared__ alignas(16) short Vs[2][2][8 * 512];   // 32KB

    const int tid  = threadIdx.x;
    const int w    = tid >> 6;               // 0..7
    const int l    = tid & 63;
    const int quad = l >> 4;
    const int l16  = l & 15;
    const int wq   = w & 3;                  // q subtile (32 rows)
    const int pr   = w >> 2;                 // s parity

    const int bh = blockIdx.x & 31;          // blk%8 = bh%8 -> XCD locality
    const int qt = blockIdx.x >> 5;
    const int b  = bh >> 4, h = bh & 15;

    const int qrow0 = qt * 128 + wq * 32;

    const short* kp_h = kp + (size_t)bh * 131072;   // 32 chunks x 8 groups x 512
    const short* vp_h = vt + (size_t)bh * 131072;   // 32 chunks x 8 groups x 512

    // prologue: stage super-pair 0 (chunks 0,1) into superbuf 0.
    // wave w stages group w of {K,V} x {even,odd} -> 4 gl_lds.
    gl_lds(kp_h + ((size_t)(0 * 8 + w)) * 512 + l * 8, &Ks[0][0][w * 512]);
    gl_lds(vp_h + ((size_t)(0 * 8 + w)) * 512 + l * 8, &Vs[0][0][w * 512]);
    gl_lds(kp_h + ((size_t)(1 * 8 + w)) * 512 + l * 8, &Ks[0][1][w * 512]);
    gl_lds(vp_h + ((size_t)(1 * 8 + w)) * 512 + l * 8, &Vs[0][1][w * 512]);

    // Q B-frags from fp32, scaled by 0.125*log2e (folds 1/sqrt(d) and exp2 base)
    const float SQ = 0.125f * 1.4426950408889634f;
    s16x8 aq[2][2];
#pragma unroll
    for (int mi = 0; mi < 2; ++mi)
#pragma unroll
        for (int c = 0; c < 2; ++c) {
            const float* p = x + (size_t)(b * Tn + qrow0 + mi * 16 + l16) * Wd
                               + h * Dh + c * 32 + quad * 8;
            float4 a = ((const float4*)p)[0], bb = ((const float4*)p)[1];
            s16x8 o;
            o[0] = f2bf(a.x * SQ); o[1] = f2bf(a.y * SQ); o[2] = f2bf(a.z * SQ); o[3] = f2bf(a.w * SQ);
            o[4] = f2bf(bb.x * SQ); o[5] = f2bf(bb.y * SQ); o[6] = f2bf(bb.z * SQ); o[7] = f2bf(bb.w * SQ);
            aq[mi][c] = o;
        }

    f32x4 oacc[2][4], dnacc[2];
#pragma unroll
    for (int mi = 0; mi < 2; ++mi) {
#pragma unroll
        for (int nt = 0; nt < 4; ++nt) {
            oacc[mi][nt][0] = 0.f; oacc[mi][nt][1] = 0.f;
            oacc[mi][nt][2] = 0.f; oacc[mi][nt][3] = 0.f;
        }
        dnacc[mi][0] = 0.f; dnacc[mi][1] = 0.f;
        dnacc[mi][2] = 0.f; dnacc[mi][3] = 0.f;
    }

    s16x8 ones;
#pragma unroll
    for (int j = 0; j < 8; ++j) ones[j] = (short)0x3F80;   // bf16 1.0

    const f32x4 z = {0.f, 0.f, 0.f, 0.f};
    const int NSIT = Sn / 128;               // 16 super-iters (2 chunks each)

    // chunk-pair-0 staging (and Q loads) must be complete before first reads
    asm volatile("s_waitcnt vmcnt(0)" ::: "memory");
    __syncthreads();

    for (int t = 0; t < NSIT; ++t) {
        const int sb = t & 1;

        // stage next super-pair (chunks 2t+2, 2t+3) into the alternate slots
        if (t + 1 < NSIT) {
            const size_t c0 = (size_t)(2 * t + 2) * 8;
            gl_lds(kp_h + (c0 + w) * 512 + l * 8,     &Ks[sb ^ 1][0][w * 512]);
            gl_lds(vp_h + (c0 + w) * 512 + l * 8,     &Vs[sb ^ 1][0][w * 512]);
            gl_lds(kp_h + (c0 + 8 + w) * 512 + l * 8, &Ks[sb ^ 1][1][w * 512]);
            gl_lds(vp_h + (c0 + 8 + w) * 512 + l * 8, &Vs[sb ^ 1][1][w * 512]);
        }

        const short* Kb = &Ks[sb][pr][0];
        const short* Vb = &Vs[sb][pr][0];

        // ---- fragment reads: contiguous 1KB ds_read_b128, conflict-free ----
        s16x8 kf[4][2];
#pragma unroll
        for (int sj = 0; sj < 4; ++sj)
#pragma unroll
            for (int g = 0; g < 2; ++g)
                kf[sj][g] = *(const s16x8*)&Kb[(sj * 2 + g) * 512 + l * 8];

        // ---- QK (swapped): sc[mi][sj] = K-tile(sj) . Q(mi)^T ----
        f32x4 sc[2][4];
        __builtin_amdgcn_s_setprio(1);
#pragma unroll
        for (int sj = 0; sj < 4; ++sj)
#pragma unroll
            for (int mi = 0; mi < 2; ++mi) {
                sc[mi][sj] = MFMA(kf[sj][0], aq[mi][0], z);
                sc[mi][sj] = MFMA(kf[sj][1], aq[mi][1], sc[mi][sj]);
            }
        __builtin_amdgcn_s_setprio(0);

        // ---- exp2 + pack to PV A-frags fully in-register ----
        s16x8 ap[2][2];
#pragma unroll
        for (int mi = 0; mi < 2; ++mi) {
            float ex[4][4];
#pragma unroll
            for (int sj = 0; sj < 4; ++sj)
#pragma unroll
                for (int r = 0; r < 4; ++r)
                    ex[sj][r] = __builtin_amdgcn_exp2f(sc[mi][sj][r]);
#pragma unroll
            for (int g = 0; g < 2; ++g) {
                u32x4 pk;
                pk[0] = cvtpk(ex[2 * g][0],     ex[2 * g][1]);
                pk[1] = cvtpk(ex[2 * g][2],     ex[2 * g][3]);
                pk[2] = cvtpk(ex[2 * g + 1][0], ex[2 * g + 1][1]);
                pk[3] = cvtpk(ex[2 * g + 1][2], ex[2 * g + 1][3]);
                ap[mi][g] = __builtin_bit_cast(s16x8, pk);
            }
        }

        // ---- V fragment reads ----
        s16x8 vf[4][2];
#pragma unroll
        for (int nt = 0; nt < 4; ++nt)
#pragma unroll
            for (int g = 0; g < 2; ++g)
                vf[nt][g] = *(const s16x8*)&Vb[(nt * 2 + g) * 512 + l * 8];

        // ---- denominator (ones-column MFMA) + PV ----
        __builtin_amdgcn_s_setprio(1);
#pragma unroll
        for (int mi = 0; mi < 2; ++mi) {
            dnacc[mi] = MFMA(ap[mi][0], ones, dnacc[mi]);
            dnacc[mi] = MFMA(ap[mi][1], ones, dnacc[mi]);
        }
#pragma unroll
        for (int mi = 0; mi < 2; ++mi)
#pragma unroll
            for (int nt = 0; nt < 4; ++nt) {
                oacc[mi][nt] = MFMA(ap[mi][0], vf[nt][0], oacc[mi][nt]);
                oacc[mi][nt] = MFMA(ap[mi][1], vf[nt][1], oacc[mi][nt]);
            }
        __builtin_amdgcn_s_setprio(0);

        // next super-pair must be fully landed before any wave reads it
        asm volatile("s_waitcnt vmcnt(0)" ::: "memory");
        __syncthreads();
    }

    // ---- combine parity partners via LDS (reuse K/V buffers) ----
    // odd-parity waves deposit partial O (32KB) and dn; even waves reduce,
    // normalize, store.  q-local index = wq*32 + mi*16 + quad*4 + r.
    float* ob = (float*)&Ks[0][0][0];        // 128 q x 64 d fp32 = 32 KB
    float* db = (float*)&Vs[0][0][0];        // 128 q fp32
    if (pr == 1) {
#pragma unroll
        for (int mi = 0; mi < 2; ++mi) {
#pragma unroll
            for (int r = 0; r < 4; ++r) {
                int ql = wq * 32 + mi * 16 + quad * 4 + r;
#pragma unroll
                for (int nt = 0; nt < 4; ++nt)
                    ob[ql * 64 + nt * 16 + l16] = oacc[mi][nt][r];
                if (l16 == 0) db[ql] = dnacc[mi][r];
            }
        }
    }
    __syncthreads();
    if (pr == 0) {
#pragma unroll
        for (int mi = 0; mi < 2; ++mi)
#pragma unroll
            for (int r = 0; r < 4; ++r) {
                int ql = wq * 32 + mi * 16 + quad * 4 + r;
                float inv = 1.0f / (dnacc[mi][r] + db[ql]);
                int t = qrow0 + mi * 16 + quad * 4 + r;
#pragma unroll
                for (int nt = 0; nt < 4; ++nt) {
                    float v = oacc[mi][nt][r] + ob[ql * 64 + nt * 16 + l16];
                    ao[(size_t)(b * Tn + t) * Wd + h * Dh + nt * 16 + l16] = f2bf(v * inv);
                }
            }
    }
}

#define LSTR 40   // proj LDS row stride (80 B = 5*16: b128-aligned, 2-way banks)

// ---------------------------------------------------------------------------
// Projection GEMM, double-buffered + async reg-staged prefetch, 1 barrier/iter:
// out[4096][1024] = A(bf16)[M][K] @ Wb(bf16)[N][K]^T + bias, fp32 out.
// Block 256 = 4 waves; tile 128m x 64n x 32k; wave = 64m x 32n (8 MFMA/chunk).
// ---------------------------------------------------------------------------
__global__ __launch_bounds__(256, 2) void proj_gemm(
    const short* __restrict__ A, const short* __restrict__ Wb,
    const float* __restrict__ bias, float* __restrict__ out)
{
    __shared__ alignas(16) short As[2][128 * LSTR];
    __shared__ alignas(16) short Bs[2][64 * LSTR];

    const int tid  = threadIdx.x;
    const int w    = tid >> 6;
    const int l    = tid & 63;
    const int quad = l >> 4;
    const int l16  = l & 15;

    const int bn = blockIdx.x & 15;    // 16 n-tiles
    const int bm = blockIdx.x >> 4;    // 32 m-tiles
    const int m0 = bm * 128;
    const int n0 = bn * 64;
    const int wm = (w & 1) * 64;       // wave m-offset
    const int wn = (w >> 1) * 32;      // wave n-offset

    const int rr = tid >> 2;   // staging row 0..63
    const int sg = tid & 3;    // 16B segment 0..3 (BK=32 shorts = 64B row)

    f32x4 acc[4][2];
#pragma unroll
    for (int mi = 0; mi < 4; ++mi)
#pragma unroll
        for (int nt = 0; nt < 2; ++nt) {
            acc[mi][nt][0] = 0.f; acc[mi][nt][1] = 0.f;
            acc[mi][nt][2] = 0.f; acc[mi][nt][3] = 0.f;
        }

    // prologue: stage k-chunk 0 into buffer 0
    s16x8 ra0 = ld8(A  + (size_t)(m0 + rr) * Wd + sg * 8);
    s16x8 ra1 = ld8(A  + (size_t)(m0 + 64 + rr) * Wd + sg * 8);
    s16x8 rb  = ld8(Wb + (size_t)(n0 + rr) * Wd + sg * 8);
    *(s16x8*)&As[0][rr * LSTR + sg * 8]        = ra0;
    *(s16x8*)&As[0][(rr + 64) * LSTR + sg * 8] = ra1;
    *(s16x8*)&Bs[0][rr * LSTR + sg * 8]        = rb;
    __syncthreads();

    for (int k0 = 0; k0 < Wd; k0 += 32) {
        const int p = (k0 >> 5) & 1;

        if (k0 + 32 < Wd) {
            ra0 = ld8(A  + (size_t)(m0 + rr) * Wd + k0 + 32 + sg * 8);
            ra1 = ld8(A  + (size_t)(m0 + 64 + rr) * Wd + k0 + 32 + sg * 8);
            rb  = ld8(Wb + (size_t)(n0 + rr) * Wd + k0 + 32 + sg * 8);
        }

        s16x8 a[4], bw[2];
#pragma unroll
        for (int mi = 0; mi < 4; ++mi)
            a[mi] = *(const s16x8*)&As[p][(wm + mi * 16 + l16) * LSTR + quad * 8];
#pragma unroll
        for (int nt = 0; nt < 2; ++nt)
            bw[nt] = *(const s16x8*)&Bs[p][(wn + nt * 16 + l16) * LSTR + quad * 8];
        __builtin_amdgcn_s_setprio(1);
#pragma unroll
        for (int mi = 0; mi < 4; ++mi)
#pragma unroll
            for (int nt = 0; nt < 2; ++nt)
                acc[mi][nt] = MFMA(a[mi], bw[nt], acc[mi][nt]);
        __builtin_amdgcn_s_setprio(0);

        if (k0 + 32 < Wd) {
            *(s16x8*)&As[p ^ 1][rr * LSTR + sg * 8]        = ra0;
            *(s16x8*)&As[p ^ 1][(rr + 64) * LSTR + sg * 8] = ra1;
            *(s16x8*)&Bs[p ^ 1][rr * LSTR + sg * 8]        = rb;
        }
        __syncthreads();
    }

#pragma unroll
    for (int nt = 0; nt < 2; ++nt) {
        float bv = bias[n0 + wn + nt * 16 + l16];
#pragma unroll
        for (int mi = 0; mi < 4; ++mi)
#pragma unroll
            for (int r = 0; r < 4; ++r)
                out[(size_t)(m0 + wm + mi * 16 + quad * 4 + r) * Wd + n0 + wn + nt * 16 + l16] =
                    acc[mi][nt][r] + bv;
    }
}

extern "C" void kernel_launch(void* const* d_in, const int* in_sizes, int n_in,
                              void* d_out, int out_size, void* d_ws, size_t ws_size,
                              hipStream_t stream) {
    const float* x  = (const float*)d_in[0];   // [2,2048,1024] fp32
    const float* ck = (const float*)d_in[1];   // [2,2048,1024] fp32
    const float* cv = (const float*)d_in[2];   // [2,2048,1024] fp32
    const float* wp = (const float*)d_in[3];   // [1024,1024]   fp32
    const float* bp = (const float*)d_in[4];   // [1024]        fp32

    const int nX = Bn * Tn * Wd;   // 4,194,304
    const int nW = Wd * Wd;        // 1,048,576

    short* kpb = (short*)d_ws;     // 8 MB  (K, MFMA A-frag packed)
    short* vpb = kpb + nX;         // 8 MB  (V^T, MFMA B-frag packed + s-perm)
    short* wbb = vpb + nX;         // 2 MB  (Wp bf16)
    short* am  = wbb + nW;         // 8 MB  (attention output, bf16)

    prep<<<dim3(2048 + nW / 2048), dim3(256), 0, stream>>>(ck, cv, wp, kpb, vpb, wbb);

    attn_fused<<<dim3(Bn * Hn * (Tn / 128)), dim3(512), 0, stream>>>(x, kpb, vpb, am);
    proj_gemm<<<dim3((Bn * Tn / 128) * (Wd / 64)), dim3(256), 0, stream>>>(
        am, wbb, bp, (float*)d_out);
}

// Round 8
// 148.894 us; speedup vs baseline: 1.0382x; 1.0332x over previous
//
#include <hip/hip_runtime.h>

#define Bn 2
#define Hn 16
#define Tn 2048
#define Sn 2048
#define Wd 1024
#define Dh 64

typedef __attribute__((ext_vector_type(8))) short s16x8;
typedef __attribute__((ext_vector_type(4))) short s16x4;
typedef __attribute__((ext_vector_type(4))) float f32x4;
typedef __attribute__((ext_vector_type(4))) unsigned u32x4;

#define MFMA(a, b, c) __builtin_amdgcn_mfma_f32_16x16x32_bf16((a), (b), (c), 0, 0, 0)

__device__ __forceinline__ s16x8 ld8(const short* p) { return *(const s16x8*)p; }

// fp32 -> bf16 round-to-nearest-even
__device__ __forceinline__ short f2bf(float f) {
    unsigned u = __builtin_bit_cast(unsigned, f);
    u += 0x7FFFu + ((u >> 16) & 1u);
    return (short)(u >> 16);
}

// pack 2 f32 -> 2 bf16 (RNE) in one instruction
__device__ __forceinline__ unsigned cvtpk(float lo, float hi) {
    unsigned r;
    asm("v_cvt_pk_bf16_f32 %0, %1, %2" : "=v"(r) : "v"(lo), "v"(hi));
    return r;
}

// async global->LDS, 16B/lane: LDS dest = wave-uniform base + lane*16
__device__ __forceinline__ void gl_lds(const short* g, short* lds) {
    __builtin_amdgcn_global_load_lds(
        (const __attribute__((address_space(1))) void*)g,
        (__attribute__((address_space(3))) void*)lds, 16, 0, 0);
}

// ---------------------------------------------------------------------------
// prep: single launch doing all preprocessing.
//   blk <  1024 : K-pack  -> kp, MFMA A-frag order:
//                 group (bh, t16 = s/16, g): 64 lanes x 16B; lane l=(quad,l16),
//                 elem j = K[b][t16*16+l16][h*64 + g*32 + quad*8 + j]  (bf16)
//   blk <  2048 : V-pack  -> vp, MFMA B-frag order with s-permutation matched
//                 to attn's in-register P frags:
//                 group (bh, sc = s/64, nt, g): lane l, elem j =
//                 V[b][sc*64 + 16*(2g+(j>>2)) + quad*4 + (j&3)][h*64+nt*16+l16]
//   blk >= 2048 : w_proj fp32 -> bf16 bulk convert
// Fragment groups are contiguous 1KB: attn stages them with global_load_lds
// (linear lane*16 scatter) and reads them as conflict-free ds_read_b128.
// ---------------------------------------------------------------------------
__global__ __launch_bounds__(256) void prep(const float* __restrict__ ck,
                                            const float* __restrict__ cv,
                                            const float* __restrict__ wp,
                                            short* __restrict__ kp,
                                            short* __restrict__ vp,
                                            short* __restrict__ wb)
{
    __shared__ short T[64][72];   // 64x64 bf16 tile, stride 144B (9*16: b128-aligned)
    const int blk = blockIdx.x;
    const int tid = threadIdx.x;
    if (blk < 2048) {
        const int isV = blk >> 10;           // 0 = kpack, 1 = vpack
        const int c   = blk & 1023;
        const int bh = c >> 5, sc = c & 31;
        const int b = bh >> 4, h = bh & 15;
        const float* src = (isV ? cv : ck) + (size_t)(b * Sn + sc * 64) * Wd + h * Dh;
#pragma unroll
        for (int i = 0; i < 4; ++i) {
            int f = i * 256 + tid, sr = f >> 4, c4 = f & 15;
            float4 v = *(const float4*)(src + (size_t)sr * Wd + c4 * 4);
            s16x4 o;
            o[0] = f2bf(v.x); o[1] = f2bf(v.y); o[2] = f2bf(v.z); o[3] = f2bf(v.w);
            *(s16x4*)&T[sr][c4 * 4] = o;
        }
        __syncthreads();
        const int rt = tid >> 6;             // t16-local (K) or nt (V), 0..3
        const int l = tid & 63, quad = l >> 4, l16 = l & 15;
        if (!isV) {
            size_t base = ((size_t)((bh * 128 + sc * 4 + rt) * 2)) * 512 + l * 8;
            *(s16x8*)(kp + base)       = *(const s16x8*)&T[rt * 16 + l16][quad * 8];
            *(s16x8*)(kp + base + 512) = *(const s16x8*)&T[rt * 16 + l16][32 + quad * 8];
        } else {
#pragma unroll
            for (int g = 0; g < 2; ++g) {
                s16x8 o;
#pragma unroll
                for (int j = 0; j < 8; ++j) {
                    int s = 32 * g + 16 * (j >> 2) + quad * 4 + (j & 3);
                    o[j] = T[s][rt * 16 + l16];
                }
                *(s16x8*)(vp + ((size_t)((bh * 32 + sc) * 8 + rt * 2 + g)) * 512 + l * 8) = o;
            }
        }
    } else {
        int i = ((blk - 2048) * 256 + tid) * 8;
        float4 a = *(const float4*)(wp + i);
        float4 b = *(const float4*)(wp + i + 4);
        s16x8 o;
        o[0] = f2bf(a.x); o[1] = f2bf(a.y); o[2] = f2bf(a.z); o[3] = f2bf(a.w);
        o[4] = f2bf(b.x); o[5] = f2bf(b.y); o[6] = f2bf(b.z); o[7] = f2bf(b.w);
        *(s16x8*)(wb + i) = o;
    }
}

// ---------------------------------------------------------------------------
// Attention, S-parity split (unchanged from R7): 8 waves (512 thr); wave w =
// (q-subtile w&3 of 32 rows, s-parity w>>2).  K/V staged as packed 1KB
// fragment groups via global_load_lds, [superbuf][parity] slots, one
// vmcnt(0)+barrier per super-iter.  Partial O/dn combined across parity
// partners through LDS at the end.  Grid 512, blk%8 = bh%8 -> XCD locality.
// ---------------------------------------------------------------------------
__global__ __launch_bounds__(512, 4) void attn_fused(
    const float* __restrict__ x, const short* __restrict__ kp,
    const short* __restrict__ vt, short* __restrict__ ao)
{
    __shared__ alignas(16) short Ks[2][2][8 * 512];   // [superbuf][parity] 32KB
    __shared__ alignas(16) short Vs[2][2][8 * 512];   // 32KB

    const int tid  = threadIdx.x;
    const int w    = tid >> 6;               // 0..7
    const int l    = tid & 63;
    const int quad = l >> 4;
    const int l16  = l & 15;
    const int wq   = w & 3;                  // q subtile (32 rows)
    const int pr   = w >> 2;                 // s parity

    const int bh = blockIdx.x & 31;          // blk%8 = bh%8 -> XCD locality
    const int qt = blockIdx.x >> 5;
    const int b  = bh >> 4, h = bh & 15;

    const int qrow0 = qt * 128 + wq * 32;

    const short* kp_h = kp + (size_t)bh * 131072;   // 32 chunks x 8 groups x 512
    const short* vp_h = vt + (size_t)bh * 131072;   // 32 chunks x 8 groups x 512

    // prologue: stage super-pair 0 (chunks 0,1) into superbuf 0.
    gl_lds(kp_h + ((size_t)(0 * 8 + w)) * 512 + l * 8, &Ks[0][0][w * 512]);
    gl_lds(vp_h + ((size_t)(0 * 8 + w)) * 512 + l * 8, &Vs[0][0][w * 512]);
    gl_lds(kp_h + ((size_t)(1 * 8 + w)) * 512 + l * 8, &Ks[0][1][w * 512]);
    gl_lds(vp_h + ((size_t)(1 * 8 + w)) * 512 + l * 8, &Vs[0][1][w * 512]);

    // Q B-frags from fp32, scaled by 0.125*log2e (folds 1/sqrt(d) and exp2 base)
    const float SQ = 0.125f * 1.4426950408889634f;
    s16x8 aq[2][2];
#pragma unroll
    for (int mi = 0; mi < 2; ++mi)
#pragma unroll
        for (int c = 0; c < 2; ++c) {
            const float* p = x + (size_t)(b * Tn + qrow0 + mi * 16 + l16) * Wd
                               + h * Dh + c * 32 + quad * 8;
            float4 a = ((const float4*)p)[0], bb = ((const float4*)p)[1];
            s16x8 o;
            o[0] = f2bf(a.x * SQ); o[1] = f2bf(a.y * SQ); o[2] = f2bf(a.z * SQ); o[3] = f2bf(a.w * SQ);
            o[4] = f2bf(bb.x * SQ); o[5] = f2bf(bb.y * SQ); o[6] = f2bf(bb.z * SQ); o[7] = f2bf(bb.w * SQ);
            aq[mi][c] = o;
        }

    f32x4 oacc[2][4], dnacc[2];
#pragma unroll
    for (int mi = 0; mi < 2; ++mi) {
#pragma unroll
        for (int nt = 0; nt < 4; ++nt) {
            oacc[mi][nt][0] = 0.f; oacc[mi][nt][1] = 0.f;
            oacc[mi][nt][2] = 0.f; oacc[mi][nt][3] = 0.f;
        }
        dnacc[mi][0] = 0.f; dnacc[mi][1] = 0.f;
        dnacc[mi][2] = 0.f; dnacc[mi][3] = 0.f;
    }

    s16x8 ones;
#pragma unroll
    for (int j = 0; j < 8; ++j) ones[j] = (short)0x3F80;   // bf16 1.0

    const f32x4 z = {0.f, 0.f, 0.f, 0.f};
    const int NSIT = Sn / 128;               // 16 super-iters (2 chunks each)

    asm volatile("s_waitcnt vmcnt(0)" ::: "memory");
    __syncthreads();

    for (int t = 0; t < NSIT; ++t) {
        const int sb = t & 1;

        if (t + 1 < NSIT) {
            const size_t c0 = (size_t)(2 * t + 2) * 8;
            gl_lds(kp_h + (c0 + w) * 512 + l * 8,     &Ks[sb ^ 1][0][w * 512]);
            gl_lds(vp_h + (c0 + w) * 512 + l * 8,     &Vs[sb ^ 1][0][w * 512]);
            gl_lds(kp_h + (c0 + 8 + w) * 512 + l * 8, &Ks[sb ^ 1][1][w * 512]);
            gl_lds(vp_h + (c0 + 8 + w) * 512 + l * 8, &Vs[sb ^ 1][1][w * 512]);
        }

        const short* Kb = &Ks[sb][pr][0];
        const short* Vb = &Vs[sb][pr][0];

        s16x8 kf[4][2];
#pragma unroll
        for (int sj = 0; sj < 4; ++sj)
#pragma unroll
            for (int g = 0; g < 2; ++g)
                kf[sj][g] = *(const s16x8*)&Kb[(sj * 2 + g) * 512 + l * 8];

        f32x4 sc[2][4];
        __builtin_amdgcn_s_setprio(1);
#pragma unroll
        for (int sj = 0; sj < 4; ++sj)
#pragma unroll
            for (int mi = 0; mi < 2; ++mi) {
                sc[mi][sj] = MFMA(kf[sj][0], aq[mi][0], z);
                sc[mi][sj] = MFMA(kf[sj][1], aq[mi][1], sc[mi][sj]);
            }
        __builtin_amdgcn_s_setprio(0);

        s16x8 ap[2][2];
#pragma unroll
        for (int mi = 0; mi < 2; ++mi) {
            float ex[4][4];
#pragma unroll
            for (int sj = 0; sj < 4; ++sj)
#pragma unroll
                for (int r = 0; r < 4; ++r)
                    ex[sj][r] = __builtin_amdgcn_exp2f(sc[mi][sj][r]);
#pragma unroll
            for (int g = 0; g < 2; ++g) {
                u32x4 pk;
                pk[0] = cvtpk(ex[2 * g][0],     ex[2 * g][1]);
                pk[1] = cvtpk(ex[2 * g][2],     ex[2 * g][3]);
                pk[2] = cvtpk(ex[2 * g + 1][0], ex[2 * g + 1][1]);
                pk[3] = cvtpk(ex[2 * g + 1][2], ex[2 * g + 1][3]);
                ap[mi][g] = __builtin_bit_cast(s16x8, pk);
            }
        }

        s16x8 vf[4][2];
#pragma unroll
        for (int nt = 0; nt < 4; ++nt)
#pragma unroll
            for (int g = 0; g < 2; ++g)
                vf[nt][g] = *(const s16x8*)&Vb[(nt * 2 + g) * 512 + l * 8];

        __builtin_amdgcn_s_setprio(1);
#pragma unroll
        for (int mi = 0; mi < 2; ++mi) {
            dnacc[mi] = MFMA(ap[mi][0], ones, dnacc[mi]);
            dnacc[mi] = MFMA(ap[mi][1], ones, dnacc[mi]);
        }
#pragma unroll
        for (int mi = 0; mi < 2; ++mi)
#pragma unroll
            for (int nt = 0; nt < 4; ++nt) {
                oacc[mi][nt] = MFMA(ap[mi][0], vf[nt][0], oacc[mi][nt]);
                oacc[mi][nt] = MFMA(ap[mi][1], vf[nt][1], oacc[mi][nt]);
            }
        __builtin_amdgcn_s_setprio(0);

        asm volatile("s_waitcnt vmcnt(0)" ::: "memory");
        __syncthreads();
    }

    // ---- combine parity partners via LDS (reuse K/V buffers) ----
    float* ob = (float*)&Ks[0][0][0];        // 128 q x 64 d fp32 = 32 KB
    float* db = (float*)&Vs[0][0][0];        // 128 q fp32
    if (pr == 1) {
#pragma unroll
        for (int mi = 0; mi < 2; ++mi) {
#pragma unroll
            for (int r = 0; r < 4; ++r) {
                int ql = wq * 32 + mi * 16 + quad * 4 + r;
#pragma unroll
                for (int nt = 0; nt < 4; ++nt)
                    ob[ql * 64 + nt * 16 + l16] = oacc[mi][nt][r];
                if (l16 == 0) db[ql] = dnacc[mi][r];
            }
        }
    }
    __syncthreads();
    if (pr == 0) {
#pragma unroll
        for (int mi = 0; mi < 2; ++mi)
#pragma unroll
            for (int r = 0; r < 4; ++r) {
                int ql = wq * 32 + mi * 16 + quad * 4 + r;
                float inv = 1.0f / (dnacc[mi][r] + db[ql]);
                int t = qrow0 + mi * 16 + quad * 4 + r;
#pragma unroll
                for (int nt = 0; nt < 4; ++nt) {
                    float v = oacc[mi][nt][r] + ob[ql * 64 + nt * 16 + l16];
                    ao[(size_t)(b * Tn + t) * Wd + h * Dh + nt * 16 + l16] = f2bf(v * inv);
                }
            }
    }
}

#define LSTR2 72   // proj LDS row stride in shorts (144 B = 9*16: b128-aligned,
                   // 4-bank row rotation -> 2-way (free) on b128 reads/writes)

// ---------------------------------------------------------------------------
// Projection GEMM v2: out[4096][1024] = A(bf16)@Wb(bf16)^T + bias, fp32 out.
// 512 thr = 8 waves; tile 128m x 64n x BK=64; wave = 32m x 32n (4m x 2n grid),
// 16 MFMA/wave/iter, 16 k-iters (was 32 iters x 8 MFMA at 8 waves/CU).
// launch_bounds(512,4) + 55KB LDS -> 2 blocks/CU = 16 waves/CU (4/SIMD, 2x).
// Double-buffered reg prefetch, one barrier per k-iter.
// ---------------------------------------------------------------------------
__global__ __launch_bounds__(512, 4) void proj_gemm(
    const short* __restrict__ A, const short* __restrict__ Wb,
    const float* __restrict__ bias, float* __restrict__ out)
{
    __shared__ alignas(16) short As[2][128 * LSTR2];   // 18.4 KB each
    __shared__ alignas(16) short Bs[2][64 * LSTR2];    // 9.2 KB each

    const int tid  = threadIdx.x;
    const int w    = tid >> 6;         // 0..7
    const int l    = tid & 63;
    const int quad = l >> 4;
    const int l16  = l & 15;

    const int bn = blockIdx.x & 15;    // 16 n-tiles
    const int bm = blockIdx.x >> 4;    // 32 m-tiles
    const int m0 = bm * 128;
    const int n0 = bn * 64;
    const int wm = (w & 3) * 32;       // wave m-offset (4 m-waves)
    const int wn = (w >> 2) * 32;      // wave n-offset (2 n-waves)

    const int rr = tid >> 3;           // staging row 0..63
    const int sg = tid & 7;            // 16B segment 0..7 (BK=64 shorts = 128B row)

    f32x4 acc[2][2];
#pragma unroll
    for (int mi = 0; mi < 2; ++mi)
#pragma unroll
        for (int nt = 0; nt < 2; ++nt) {
            acc[mi][nt][0] = 0.f; acc[mi][nt][1] = 0.f;
            acc[mi][nt][2] = 0.f; acc[mi][nt][3] = 0.f;
        }

    // prologue: stage k-chunk 0 into buffer 0 (A: rows rr, rr+64; B: row rr)
    s16x8 ra0 = ld8(A  + (size_t)(m0 + rr) * Wd + sg * 8);
    s16x8 ra1 = ld8(A  + (size_t)(m0 + 64 + rr) * Wd + sg * 8);
    s16x8 rb  = ld8(Wb + (size_t)(n0 + rr) * Wd + sg * 8);
    *(s16x8*)&As[0][rr * LSTR2 + sg * 8]        = ra0;
    *(s16x8*)&As[0][(rr + 64) * LSTR2 + sg * 8] = ra1;
    *(s16x8*)&Bs[0][rr * LSTR2 + sg * 8]        = rb;
    __syncthreads();

    for (int k0 = 0; k0 < Wd; k0 += 64) {
        const int p = (k0 >> 6) & 1;

        if (k0 + 64 < Wd) {
            ra0 = ld8(A  + (size_t)(m0 + rr) * Wd + k0 + 64 + sg * 8);
            ra1 = ld8(A  + (size_t)(m0 + 64 + rr) * Wd + k0 + 64 + sg * 8);
            rb  = ld8(Wb + (size_t)(n0 + rr) * Wd + k0 + 64 + sg * 8);
        }

        // frags: a[mi][ks] (rows wm+mi*16+l16, k-half ks), bw[nt][ks]
        s16x8 a[2][2], bw[2][2];
#pragma unroll
        for (int mi = 0; mi < 2; ++mi)
#pragma unroll
            for (int ks = 0; ks < 2; ++ks)
                a[mi][ks] = *(const s16x8*)&As[p][(wm + mi * 16 + l16) * LSTR2 + ks * 32 + quad * 8];
#pragma unroll
        for (int nt = 0; nt < 2; ++nt)
#pragma unroll
            for (int ks = 0; ks < 2; ++ks)
                bw[nt][ks] = *(const s16x8*)&Bs[p][(wn + nt * 16 + l16) * LSTR2 + ks * 32 + quad * 8];

        __builtin_amdgcn_s_setprio(1);
#pragma unroll
        for (int mi = 0; mi < 2; ++mi)
#pragma unroll
            for (int nt = 0; nt < 2; ++nt) {
                acc[mi][nt] = MFMA(a[mi][0], bw[nt][0], acc[mi][nt]);
                acc[mi][nt] = MFMA(a[mi][1], bw[nt][1], acc[mi][nt]);
            }
        __builtin_amdgcn_s_setprio(0);

        if (k0 + 64 < Wd) {
            *(s16x8*)&As[p ^ 1][rr * LSTR2 + sg * 8]        = ra0;
            *(s16x8*)&As[p ^ 1][(rr + 64) * LSTR2 + sg * 8] = ra1;
            *(s16x8*)&Bs[p ^ 1][rr * LSTR2 + sg * 8]        = rb;
        }
        __syncthreads();
    }

#pragma unroll
    for (int nt = 0; nt < 2; ++nt) {
        float bv = bias[n0 + wn + nt * 16 + l16];
#pragma unroll
        for (int mi = 0; mi < 2; ++mi)
#pragma unroll
            for (int r = 0; r < 4; ++r)
                out[(size_t)(m0 + wm + mi * 16 + quad * 4 + r) * Wd + n0 + wn + nt * 16 + l16] =
                    acc[mi][nt][r] + bv;
    }
}

extern "C" void kernel_launch(void* const* d_in, const int* in_sizes, int n_in,
                              void* d_out, int out_size, void* d_ws, size_t ws_size,
                              hipStream_t stream) {
    const float* x  = (const float*)d_in[0];   // [2,2048,1024] fp32
    const float* ck = (const float*)d_in[1];   // [2,2048,1024] fp32
    const float* cv = (const float*)d_in[2];   // [2,2048,1024] fp32
    const float* wp = (const float*)d_in[3];   // [1024,1024]   fp32
    const float* bp = (const float*)d_in[4];   // [1024]        fp32

    const int nX = Bn * Tn * Wd;   // 4,194,304
    const int nW = Wd * Wd;        // 1,048,576

    short* kpb = (short*)d_ws;     // 8 MB  (K, MFMA A-frag packed)
    short* vpb = kpb + nX;         // 8 MB  (V^T, MFMA B-frag packed + s-perm)
    short* wbb = vpb + nX;         // 2 MB  (Wp bf16)
    short* am  = wbb + nW;         // 8 MB  (attention output, bf16)

    prep<<<dim3(2048 + nW / 2048), dim3(256), 0, stream>>>(ck, cv, wp, kpb, vpb, wbb);

    attn_fused<<<dim3(Bn * Hn * (Tn / 128)), dim3(512), 0, stream>>>(x, kpb, vpb, am);
    proj_gemm<<<dim3((Bn * Tn / 128) * (Wd / 64)), dim3(512), 0, stream>>>(
        am, wbb, bp, (float*)d_out);
}